// Round 1
// baseline (386.239 us; speedup 1.0000x reference)
//
#include <hip/hip_runtime.h>

#define BTOT 8192
#define SEQ 32
#define NI 16
#define NU 19
#define IPB 6
#define TPB 128
#define L2E 1.4426950408889634f

__global__ __launch_bounds__(TPB, 3) void ltc_fused(
    const float* __restrict__ xin,
    const float* __restrict__ w1, const float* __restrict__ b1,
    const float* __restrict__ w2, const float* __restrict__ b2,
    const float* __restrict__ gleak, const float* __restrict__ vleak, const float* __restrict__ cm,
    const float* __restrict__ sigma, const float* __restrict__ mu, const float* __restrict__ ww,
    const float* __restrict__ erev,
    const float* __restrict__ ssigma, const float* __restrict__ smu, const float* __restrict__ sw,
    const float* __restrict__ serev,
    const float* __restrict__ inw, const float* __restrict__ inb,
    const float* __restrict__ outw, const float* __restrict__ outb,
    const float* __restrict__ mask, const float* __restrict__ smask,
    float* __restrict__ dout)
{
    // union area: conv scratch (img 1232 + c1p 1440 floats = 10688 B)
    // later overlaid by transformed params (665 float4 = 10640 B)
    __shared__ __align__(16) float uni[2672];
    __shared__ float featL[IPB * 512];
    __shared__ float vbuf[IPB * 20];

    float* img = uni;            // 28 x 44
    float* c1p = uni + 1232;     // 6 x 12 x 20
    float4* up = (float4*)uni;          // 361 entries {A2, B2, we, wm}
    float4* sp = ((float4*)uni) + 361;  // 304 entries

    const int tid = threadIdx.x;
    const int b0 = blockIdx.x * IPB;

    // ---------------- conv phase (per image, block-cooperative) ----------------
    for (int k = 0; k < IPB; ++k) {
        const int bG = b0 + k;
        const bool valid = bG < BTOT;
        if (valid) {
            for (int idx = tid; idx < 1232; idx += TPB) img[idx] = xin[bG * 1232 + idx];
        }
        __syncthreads();
        if (valid) {
            // conv1 (1->6, 5x5) + bias + relu + 2x2 maxpool  -> c1p[6][12][20]
            for (int idx = tid; idx < 1440; idx += TPB) {
                int c = idx / 240, r = idx - c * 240;
                int y = r / 20, xx = r - y * 20;
                const float* ib = img + (2 * y) * 44 + 2 * xx;
                float win[6][6];
                #pragma unroll
                for (int rr = 0; rr < 6; ++rr) {
                    float2 a = *(const float2*)(ib + rr * 44);
                    float2 b = *(const float2*)(ib + rr * 44 + 2);
                    float2 cc = *(const float2*)(ib + rr * 44 + 4);
                    win[rr][0] = a.x; win[rr][1] = a.y; win[rr][2] = b.x;
                    win[rr][3] = b.y; win[rr][4] = cc.x; win[rr][5] = cc.y;
                }
                const float* wp = w1 + c * 25;
                float a00 = 0.f, a01 = 0.f, a10 = 0.f, a11 = 0.f;
                #pragma unroll
                for (int ky = 0; ky < 5; ++ky)
                    #pragma unroll
                    for (int kx = 0; kx < 5; ++kx) {
                        float wv = wp[ky * 5 + kx];
                        a00 = fmaf(wv, win[ky][kx], a00);
                        a01 = fmaf(wv, win[ky][kx + 1], a01);
                        a10 = fmaf(wv, win[ky + 1][kx], a10);
                        a11 = fmaf(wv, win[ky + 1][kx + 1], a11);
                    }
                float m = fmaxf(fmaxf(a00, a01), fmaxf(a10, a11)) + b1[c];
                c1p[idx] = fmaxf(m, 0.f);
            }
        }
        __syncthreads();
        if (valid) {
            // conv2 (6->16, 5x5) + bias + relu + 2x2 maxpool -> featL[k][512]
            for (int idx = tid; idx < 512; idx += TPB) {
                int c2 = idx >> 5, r = idx & 31;
                int y = r >> 3, xx = r & 7;
                float a00 = 0.f, a01 = 0.f, a10 = 0.f, a11 = 0.f;
                for (int ch = 0; ch < 6; ++ch) {
                    const float* cb = c1p + ch * 240 + (2 * y) * 20 + 2 * xx;
                    float win[6][6];
                    #pragma unroll
                    for (int rr = 0; rr < 6; ++rr) {
                        float2 a = *(const float2*)(cb + rr * 20);
                        float2 b = *(const float2*)(cb + rr * 20 + 2);
                        float2 cc = *(const float2*)(cb + rr * 20 + 4);
                        win[rr][0] = a.x; win[rr][1] = a.y; win[rr][2] = b.x;
                        win[rr][3] = b.y; win[rr][4] = cc.x; win[rr][5] = cc.y;
                    }
                    const float* wp = w2 + (c2 * 6 + ch) * 25;
                    #pragma unroll
                    for (int ky = 0; ky < 5; ++ky)
                        #pragma unroll
                        for (int kx = 0; kx < 5; ++kx) {
                            float wv = wp[ky * 5 + kx];
                            a00 = fmaf(wv, win[ky][kx], a00);
                            a01 = fmaf(wv, win[ky][kx + 1], a01);
                            a10 = fmaf(wv, win[ky + 1][kx], a10);
                            a11 = fmaf(wv, win[ky + 1][kx + 1], a11);
                        }
                }
                float m = fmaxf(fmaxf(a00, a01), fmaxf(a10, a11)) + b2[c2];
                featL[k * 512 + idx] = fmaxf(m, 0.f);
            }
        }
        __syncthreads();
    }

    // ---------------- parameter transform (overlays conv scratch) ----------------
    for (int idx = tid; idx < 665; idx += TPB) {
        if (idx < 361) {
            float s = sigma[idx];
            up[idx] = make_float4(-L2E * s, L2E * s * mu[idx],
                                  ww[idx] * erev[idx], ww[idx] * mask[idx]);
        } else {
            int kk = idx - 361;
            int i = kk / 19;
            float s = ssigma[kk];
            sp[kk] = make_float4(-L2E * s * inw[i], -L2E * s * (inb[i] - smu[kk]),
                                 sw[kk] * serev[kk], sw[kk] * smask[kk]);
        }
    }
    __syncthreads();

    // ---------------- LTC phase: 19 lanes per image, 3 images per wave ----------------
    const int wv_ = tid >> 6, l = tid & 63;
    const int g = l / 19;                 // 0..2 active, 3 = idle lanes 57..63
    const int j = l - g * 19;
    const int kimg = wv_ * 3 + g;         // 0..5
    const bool act = (g < 3) && (b0 + kimg < BTOT);
    const int kc = (kimg < IPB) ? kimg : (IPB - 1);

    float v = 0.f, gl = 0.f, gv = 0.f, cmt = 0.f;
    if (act) {
        gl = gleak[j];
        gv = gl * vleak[j];
        cmt = cm[j] * 6.f;     // cm / (dt/unfolds), dt=1, unfolds=6
        vbuf[kimg * 20 + j] = 0.f;
    }
    __builtin_amdgcn_wave_barrier();
    __asm__ volatile("" ::: "memory");

    for (int s = 0; s < SEQ; ++s) {
        const float* fb = featL + kc * 512 + s * 16;
        float wns = 0.f, wds = 0.f;
        #pragma unroll
        for (int i = 0; i < 16; ++i) {
            float fi = fb[i];
            float4 p = sp[i * 19 + j];
            float t = fmaf(p.x, fi, p.y);
            float e = __builtin_amdgcn_exp2f(t);
            float rr = __builtin_amdgcn_rcpf(1.f + e);
            wns = fmaf(p.z, rr, wns);
            wds = fmaf(p.w, rr, wds);
        }
        for (int u = 0; u < 6; ++u) {
            float num = fmaf(cmt, v, gv) + wns;
            float den = cmt + gl + wds;
            #pragma unroll
            for (int i = 0; i < 19; ++i) {
                float vi = vbuf[kc * 20 + i];
                float4 p = up[i * 19 + j];
                float t = fmaf(p.x, vi, p.y);
                float e = __builtin_amdgcn_exp2f(t);
                float rr = __builtin_amdgcn_rcpf(1.f + e);
                num = fmaf(p.z, rr, num);
                den = fmaf(p.w, rr, den);
            }
            v = num * __builtin_amdgcn_rcpf(den + 1e-8f);
            __builtin_amdgcn_wave_barrier();
            __asm__ volatile("" ::: "memory");
            if (act) vbuf[kimg * 20 + j] = v;
            __builtin_amdgcn_wave_barrier();
            __asm__ volatile("" ::: "memory");
        }
    }
    if (act && j < 2) dout[(b0 + kimg) * 2 + j] = fmaf(v, outw[j], outb[j]);
}

extern "C" void kernel_launch(void* const* d_in, const int* in_sizes, int n_in,
                              void* d_out, int out_size, void* d_ws, size_t ws_size,
                              hipStream_t stream) {
    const float* x      = (const float*)d_in[0];
    const float* w1     = (const float*)d_in[1];
    const float* b1     = (const float*)d_in[2];
    const float* w2     = (const float*)d_in[3];
    const float* b2     = (const float*)d_in[4];
    const float* gleak  = (const float*)d_in[5];
    const float* vleak  = (const float*)d_in[6];
    const float* cm     = (const float*)d_in[7];
    const float* sigma  = (const float*)d_in[8];
    const float* mu     = (const float*)d_in[9];
    const float* ww     = (const float*)d_in[10];
    const float* erev   = (const float*)d_in[11];
    const float* ssig   = (const float*)d_in[12];
    const float* smu    = (const float*)d_in[13];
    const float* sw     = (const float*)d_in[14];
    const float* serev  = (const float*)d_in[15];
    const float* inw    = (const float*)d_in[16];
    const float* inb    = (const float*)d_in[17];
    const float* outw   = (const float*)d_in[18];
    const float* outb   = (const float*)d_in[19];
    const float* mask   = (const float*)d_in[20];
    const float* smask  = (const float*)d_in[21];

    dim3 grid((BTOT + IPB - 1) / IPB), block(TPB);
    hipLaunchKernelGGL(ltc_fused, grid, block, 0, stream,
                       x, w1, b1, w2, b2, gleak, vleak, cm, sigma, mu, ww, erev,
                       ssig, smu, sw, serev, inw, inb, outw, outb, mask, smask,
                       (float*)d_out);
}